// Round 7
// baseline (51.942 us; speedup 1.0000x reference)
//
#include <hip/hip_runtime.h>
#include <cstddef>

#define N_ 16
#define L_ 512
#define D_ 256
#define M_ 3584
#define LN_EPS 1e-5f

typedef __attribute__((ext_vector_type(8))) short bf16x8;
typedef __attribute__((ext_vector_type(4))) float f32x4;

__device__ inline unsigned int f2bf_raw(float f) {
    union { float f; unsigned int u; } v; v.f = f;
    return (v.u + 0x7FFFu + ((v.u >> 16) & 1u)) >> 16;   // RNE
}
__device__ inline unsigned int pack2bf(float lo, float hi) {
    return f2bf_raw(lo) | (f2bf_raw(hi) << 16);
}
__device__ inline float bf2f(unsigned int hw) {
    union { unsigned int u; float f; } v; v.u = hw << 16; return v.f;
}
// Publish barrier: wait own LDS ops, then barrier — does NOT drain vmcnt (T4).
__device__ inline void barrier_lgkm() {
    asm volatile("s_waitcnt lgkmcnt(0)" ::: "memory");
    __builtin_amdgcn_s_barrier();
}
// XOR-swizzled byte offset in the A region (row stride 512 B)
__device__ inline int aswz(int row, int colb) {
    return row * 512 + (((colb & 0x1F0) ^ ((row & 7) << 4)) | (colb & 0xF));
}

struct ConvSM {
    unsigned char A[68 * 512];     // x rows l0-2..l0+65, then h1/h2 slots (bf16, swizzled)
    uint4 B[2][4][256];            // double-buffered weight step tiles
};
union MegaSM {
    ConvSM st;                     // 67584 B
    int es[L_];
};

// ------------------------------------------------------------------ prep ----
// blocks 0..191: two 32x32 weight-transpose tiles each (fp32 W -> step-major
//   bf16 Wst[ks][co][k&31]); blocks 192..207: per-n cumsum of target.
__global__ __launch_bounds__(512)
void prep_kernel(const float* __restrict__ W1, unsigned short* __restrict__ Wt1,
                 const float* __restrict__ W2, unsigned short* __restrict__ Wt2,
                 const int* __restrict__ target, int* __restrict__ ends) {
    __shared__ union { float t[2][32][33]; int s[L_]; } sm;
    const int bid = blockIdx.x;
    if (bid < 192) {
        const int half = threadIdx.x >> 8, st = threadIdx.x & 255;
        const int t = bid * 2 + half;                 // tile id 0..383
        const int kb = (t % 24) * 32;
        const int cb = ((t / 24) % 8) * 32;
        const float* W = (t >= 192) ? W2 : W1;
        unsigned short* Wt = (t >= 192) ? Wt2 : Wt1;
        const int tx = st & 31, ty = st >> 5;
#pragma unroll
        for (int r = 0; r < 32; r += 8)
            sm.t[half][ty + r][tx] = W[(size_t)(kb + ty + r) * 256 + cb + tx];
        __syncthreads();
#pragma unroll
        for (int r = 0; r < 32; r += 8)
            Wt[(size_t)(kb >> 5) * 8192 + (size_t)(cb + ty + r) * 32 + tx] =
                (unsigned short)f2bf_raw(sm.t[half][tx][ty + r]);
    } else {
        const int n = bid - 192, t = threadIdx.x;
        sm.s[t] = target[n * L_ + t];
        __syncthreads();
        for (int off = 1; off < L_; off <<= 1) {
            int v = (t >= off) ? sm.s[t - off] : 0;
            __syncthreads();
            sm.s[t] += v;
            __syncthreads();
        }
        ends[n * L_ + t] = sm.s[t];
    }
}

// ------------------------------------------------ K-loop (shared by convs) --
// NR row-groups of 16; wave wv owns cols [wv*32, wv*32+32). B double-buffered,
// regs hold next step (loads issued 1 step early); lgkm-only barrier per step.
template <int NR, bool CLAMP>
__device__ __forceinline__ void conv_kloop(MegaSM* sm, const unsigned short* __restrict__ Wst,
                                           int tid, int wc, int fr, int fg,
                                           f32x4 (&acc)[NR][2]) {
    const int bco = tid >> 1;
    const int bq0 = (tid & 1) * 2;
    const unsigned short* wbase = Wst + (size_t)bco * 32 + (tid & 1) * 16;

    uint4 c0, c1, n0, n1;
    c0 = *(const uint4*)(wbase);
    c1 = *(const uint4*)(wbase + 8);
    sm->st.B[0][bq0][bco] = c0;
    sm->st.B[0][bq0 + 1][bco] = c1;
    c0 = *(const uint4*)(wbase + 8192);
    c1 = *(const uint4*)(wbase + 8192 + 8);
    barrier_lgkm();                        // publishes buf0 + caller's A writes

    for (int ks = 0; ks < 24; ++ks) {
        if (ks < 22) {
            const unsigned short* wp = wbase + (size_t)(ks + 2) * 8192;
            n0 = *(const uint4*)(wp);
            n1 = *(const uint4*)(wp + 8);
        }
        const int koff = ks >> 3;
        const int cb = (ks & 7) * 64 + fg * 16;
        bf16x8 av[NR], bv0, bv1;
#pragma unroll
        for (int r = 0; r < NR; ++r) {
            int ar = r * 16 + fr + koff;
            if (CLAMP) ar = (ar > 67) ? 67 : ar;
            av[r] = *(const bf16x8*)(sm->st.A + ar * 512 + ((cb ^ ((ar & 7) << 4))));
        }
        bv0 = *(const bf16x8*)&sm->st.B[ks & 1][fg][wc + fr];
        bv1 = *(const bf16x8*)&sm->st.B[ks & 1][fg][wc + 16 + fr];
#pragma unroll
        for (int r = 0; r < NR; ++r) {
            acc[r][0] = __builtin_amdgcn_mfma_f32_16x16x32_bf16(av[r], bv0, acc[r][0], 0, 0, 0);
            acc[r][1] = __builtin_amdgcn_mfma_f32_16x16x32_bf16(av[r], bv1, acc[r][1], 0, 0, 0);
        }
        if (ks < 23) {
            sm->st.B[(ks + 1) & 1][bq0][bco] = c0;
            sm->st.B[(ks + 1) & 1][bq0 + 1][bco] = c1;
        }
        c0 = n0; c1 = n1;
        barrier_lgkm();
    }
}

// ------------------------------------------------------------------ mega ----
// blocks [0,128): fused conv1+LN1+conv2+LN2+linear on a 64-row tile
//   (conv1 computes 66 rows incl. halo; h1 never leaves LDS).
// blocks [128,512): gather of 150 mel rows each.
__global__ __launch_bounds__(512, 4)
void fused_kernel(const float* __restrict__ x,
                  const unsigned short* __restrict__ W1st,
                  const unsigned short* __restrict__ W2st,
                  const float* __restrict__ b1, const float* __restrict__ g1,
                  const float* __restrict__ be1,
                  const float* __restrict__ b2, const float* __restrict__ g2,
                  const float* __restrict__ be2,
                  const float* __restrict__ lw, const float* __restrict__ lb,
                  const int* __restrict__ ends,
                  float* __restrict__ out0, float* __restrict__ log_dur) {
    __shared__ MegaSM sm;
    const int tid = threadIdx.x;
    const int lane = tid & 63, wv = tid >> 6;

    if (blockIdx.x >= 128) {
        // ------------------------------ gather role ------------------------
        const int g = blockIdx.x - 128;          // 0..383
        const int n = g / 24;
        const int m0 = (g % 24) * 150;
        sm.es[tid] = ends[n * L_ + tid];
        __syncthreads();
        const int total = sm.es[L_ - 1];
        const int mend = (m0 + 150 < M_) ? (m0 + 150) : M_;
#pragma unroll 2
        for (int i = 0; i < 19; ++i) {
            int m = m0 + i * 8 + wv;
            if (m < mend) {
                float4 o = {0.f, 0.f, 0.f, 0.f};
                if (m < total) {
                    int lo = -1, hi = L_ - 1;    // first hi with es[hi] > m
                    while (hi - lo > 1) {
                        int mid = (lo + hi) >> 1;
                        if (sm.es[mid] > m) hi = mid; else lo = mid;
                    }
                    o = *(const float4*)&x[((size_t)n * L_ + hi) * D_ + lane * 4];
                }
                *(float4*)&out0[((size_t)n * M_ + m) * D_ + lane * 4] = o;
            }
        }
        return;
    }

    // ---------------------------------- conv role --------------------------
    const int row0 = blockIdx.x * 64;
    const int n = row0 >> 9, l0 = row0 & 511;
    const int wc = wv * 32;                       // wave's 32-co column strip
    const int fr = lane & 15, fg = lane >> 4;

    // ---- stage x once: slots r=0..67 <-> l = l0-2+r, bf16, swizzled ----
    for (int idx = tid; idx < 68 * 64; idx += 512) {
        int r = idx >> 6, c4 = idx & 63;
        int l = l0 - 2 + r;
        float4 v = {0.f, 0.f, 0.f, 0.f};
        if (l >= 0 && l < L_)
            v = ((const float4*)(x + ((size_t)(n * L_ + l)) * D_))[c4];
        uint2 p;
        p.x = pack2bf(v.x, v.y);
        p.y = pack2bf(v.z, v.w);
        *(uint2*)(sm.st.A + aswz(r, c4 * 8)) = p;
    }

    // ---- conv1: 66 output rows (5 row-groups, padded), cols = all 256 ----
    f32x4 acc1[5][2];
#pragma unroll
    for (int r = 0; r < 5; ++r) { acc1[r][0] = (f32x4){0,0,0,0}; acc1[r][1] = (f32x4){0,0,0,0}; }
    conv_kloop<5, true>(&sm, W1st, tid, wc, fr, fg, acc1);

    // epilogue: relu+bias -> bf16 into A slots mm=0..65 (x is dead)
    {
        const float bs0 = b1[wc + fr], bs1 = b1[wc + 16 + fr];
#pragma unroll
        for (int r = 0; r < 5; ++r)
#pragma unroll
            for (int q = 0; q < 4; ++q) {
                const int mm = r * 16 + fg * 4 + q;
                if (mm < 66) {
                    float v0 = fmaxf(acc1[r][0][q] + bs0, 0.f);
                    float v1 = fmaxf(acc1[r][1][q] + bs1, 0.f);
                    *(unsigned short*)(sm.st.A + aswz(mm, 2 * (wc + fr))) =
                        (unsigned short)f2bf_raw(v0);
                    *(unsigned short*)(sm.st.A + aswz(mm, 2 * (wc + 16 + fr))) =
                        (unsigned short)f2bf_raw(v1);
                }
            }
    }
    __syncthreads();

    // ---- LN1 in place (bf16 rows); zero pad rows so conv2 SAME-pad is exact
    {
        const float4 gv = *(const float4*)&g1[lane * 4];
        const float4 bv = *(const float4*)&be1[lane * 4];
        for (int mm = wv; mm < 66; mm += 8) {
            const int hrow = l0 + mm - 1;
            const int addr = aswz(mm, lane * 8);
            if (hrow < 0 || hrow >= L_) {
                *(uint2*)(sm.st.A + addr) = (uint2){0u, 0u};
                continue;
            }
            uint2 pv = *(uint2*)(sm.st.A + addr);
            float v0 = bf2f(pv.x & 0xFFFFu), v1 = bf2f(pv.x >> 16);
            float v2 = bf2f(pv.y & 0xFFFFu), v3 = bf2f(pv.y >> 16);
            float s = v0 + v1 + v2 + v3;
            float ss = v0 * v0 + v1 * v1 + v2 * v2 + v3 * v3;
#pragma unroll
            for (int off = 32; off; off >>= 1) {
                s += __shfl_xor(s, off);
                ss += __shfl_xor(ss, off);
            }
            const float mu = s * (1.f / D_);
            const float var = ss * (1.f / D_) - mu * mu;
            const float rs = rsqrtf(var + LN_EPS);
            uint2 o;
            o.x = pack2bf((v0 - mu) * rs * gv.x + bv.x, (v1 - mu) * rs * gv.y + bv.y);
            o.y = pack2bf((v2 - mu) * rs * gv.z + bv.z, (v3 - mu) * rs * gv.w + bv.w);
            *(uint2*)(sm.st.A + addr) = o;
        }
    }
    __syncthreads();

    // ---- conv2: 64 output rows (4 row-groups) over LN1'd h1 slots ----
    f32x4 acc2[4][2];
#pragma unroll
    for (int r = 0; r < 4; ++r) { acc2[r][0] = (f32x4){0,0,0,0}; acc2[r][1] = (f32x4){0,0,0,0}; }
    conv_kloop<4, false>(&sm, W2st, tid, wc, fr, fg, acc2);

    // epilogue: relu+bias -> bf16 into A slots mm=0..63 (h1 is dead)
    {
        const float bs0 = b2[wc + fr], bs1 = b2[wc + 16 + fr];
#pragma unroll
        for (int r = 0; r < 4; ++r)
#pragma unroll
            for (int q = 0; q < 4; ++q) {
                const int mm = r * 16 + fg * 4 + q;
                float v0 = fmaxf(acc2[r][0][q] + bs0, 0.f);
                float v1 = fmaxf(acc2[r][1][q] + bs1, 0.f);
                *(unsigned short*)(sm.st.A + aswz(mm, 2 * (wc + fr))) =
                    (unsigned short)f2bf_raw(v0);
                *(unsigned short*)(sm.st.A + aswz(mm, 2 * (wc + 16 + fr))) =
                    (unsigned short)f2bf_raw(v1);
            }
    }
    __syncthreads();

    // ---- LN2 + linear -> log_dur ----
    {
        const float4 gv = *(const float4*)&g2[lane * 4];
        const float4 bv = *(const float4*)&be2[lane * 4];
        const float4 wvv = *(const float4*)&lw[lane * 4];
        for (int mm = wv; mm < 64; mm += 8) {
            uint2 pv = *(uint2*)(sm.st.A + aswz(mm, lane * 8));
            float v0 = bf2f(pv.x & 0xFFFFu), v1 = bf2f(pv.x >> 16);
            float v2 = bf2f(pv.y & 0xFFFFu), v3 = bf2f(pv.y >> 16);
            float s = v0 + v1 + v2 + v3;
            float ss = v0 * v0 + v1 * v1 + v2 * v2 + v3 * v3;
#pragma unroll
            for (int off = 32; off; off >>= 1) {
                s += __shfl_xor(s, off);
                ss += __shfl_xor(ss, off);
            }
            const float mu = s * (1.f / D_);
            const float var = ss * (1.f / D_) - mu * mu;
            const float rs = rsqrtf(var + LN_EPS);
            float dot = ((v0 - mu) * rs * gv.x + bv.x) * wvv.x
                      + ((v1 - mu) * rs * gv.y + bv.y) * wvv.y
                      + ((v2 - mu) * rs * gv.z + bv.z) * wvv.z
                      + ((v3 - mu) * rs * gv.w + bv.w) * wvv.w;
#pragma unroll
            for (int off = 32; off; off >>= 1) dot += __shfl_xor(dot, off);
            if (lane == 0) log_dur[row0 + mm] = dot + lb[0];
        }
    }
}

// ---------------------------------------------------------------- launch ----
extern "C" void kernel_launch(void* const* d_in, const int* in_sizes, int n_in,
                              void* d_out, int out_size, void* d_ws, size_t ws_size,
                              hipStream_t stream) {
    const float* x   = (const float*)d_in[0];
    const float* w1  = (const float*)d_in[1];
    const float* b1  = (const float*)d_in[2];
    const float* g1  = (const float*)d_in[3];
    const float* be1 = (const float*)d_in[4];
    const float* w2  = (const float*)d_in[5];
    const float* b2  = (const float*)d_in[6];
    const float* g2  = (const float*)d_in[7];
    const float* be2 = (const float*)d_in[8];
    const float* lw  = (const float*)d_in[9];
    const float* lb  = (const float*)d_in[10];
    const int* target = (const int*)d_in[11];

    float* out0 = (float*)d_out;                        // [16, 3584, 256]
    float* log_dur = out0 + (size_t)N_ * M_ * D_;       // [16, 512]

    unsigned short* w1t = (unsigned short*)d_ws;        // [24*8192] bf16
    unsigned short* w2t = w1t + 24 * 8192;              // [24*8192] bf16
    int* ends = (int*)(w2t + 24 * 8192);                // [16*512]

    prep_kernel<<<208, 512, 0, stream>>>(w1, w1t, w2, w2t, target, ends);
    fused_kernel<<<512, 512, 0, stream>>>(x, w1t, w2t, b1, g1, be1,
                                          b2, g2, be2, lw, lb, ends,
                                          out0, log_dur);
}

// Round 8
// 42.193 us; speedup vs baseline: 1.2311x; 1.2311x over previous
//
#include <hip/hip_runtime.h>
#include <cstddef>

#define N_ 16
#define L_ 512
#define D_ 256
#define M_ 3584
#define LN_EPS 1e-5f

typedef __attribute__((ext_vector_type(8))) short bf16x8;
typedef __attribute__((ext_vector_type(4))) float f32x4;

__device__ inline unsigned int f2bf_raw(float f) {
    union { float f; unsigned int u; } v; v.f = f;
    return (v.u + 0x7FFFu + ((v.u >> 16) & 1u)) >> 16;   // RNE
}
__device__ inline unsigned int pack2bf(float lo, float hi) {
    return f2bf_raw(lo) | (f2bf_raw(hi) << 16);
}
// Publish barrier: wait own LDS ops, then barrier — does NOT drain vmcnt (T4).
__device__ inline void barrier_lgkm() {
    asm volatile("s_waitcnt lgkmcnt(0)" ::: "memory");
    __builtin_amdgcn_s_barrier();
}

// ------------------------------------------------------------------ prep ----
// blocks 0..191: two 32x32 weight-transpose tiles each (fp32 W -> step-major
//   bf16 Wst[ks][co][k&31]); blocks 192..207: per-n cumsum of target.
__global__ __launch_bounds__(512)
void prep_kernel(const float* __restrict__ W1, unsigned short* __restrict__ Wt1,
                 const float* __restrict__ W2, unsigned short* __restrict__ Wt2,
                 const int* __restrict__ target, int* __restrict__ ends) {
    __shared__ union { float t[2][32][33]; int s[L_]; } sm;
    const int bid = blockIdx.x;
    if (bid < 192) {
        const int half = threadIdx.x >> 8, st = threadIdx.x & 255;
        const int t = bid * 2 + half;                 // tile id 0..383
        const int kb = (t % 24) * 32;
        const int cb = ((t / 24) % 8) * 32;
        const float* W = (t >= 192) ? W2 : W1;
        unsigned short* Wt = (t >= 192) ? Wt2 : Wt1;
        const int tx = st & 31, ty = st >> 5;
#pragma unroll
        for (int r = 0; r < 32; r += 8)
            sm.t[half][ty + r][tx] = W[(size_t)(kb + ty + r) * 256 + cb + tx];
        __syncthreads();
#pragma unroll
        for (int r = 0; r < 32; r += 8)
            Wt[(size_t)(kb >> 5) * 8192 + (size_t)(cb + ty + r) * 32 + tx] =
                (unsigned short)f2bf_raw(sm.t[half][tx][ty + r]);
    } else {
        const int n = bid - 192, t = threadIdx.x;
        sm.s[t] = target[n * L_ + t];
        __syncthreads();
        for (int off = 1; off < L_; off <<= 1) {
            int v = (t >= off) ? sm.s[t - off] : 0;
            __syncthreads();
            sm.s[t] += v;
            __syncthreads();
        }
        ends[n * L_ + t] = sm.s[t];
    }
}

// ---------------------------------------- fused conv+LN(+lin)  ||  gather ---
// Grid 640; launch_bounds(512,6) => 3 blocks/CU co-resident (LDS 49KB each).
// blocks [0,256): conv tile 32 rows x 256 co (8 waves, 1x4 frags 16x16x32).
//   A (34x256 bf16, XOR-swizzled) staged once; B DOUBLE-buffered, reg-held
//   prefetch 1 step ahead, global loads 2 steps ahead; lgkm-only barrier/step.
// blocks [256,640): gather of 75 mel rows each, m in [m_off, m_off+1792).
template <bool BF_IN, bool FINAL>
__global__ __launch_bounds__(512, 6)
void conv_gather(const void* __restrict__ in_, const unsigned short* __restrict__ Wst,
                 const float* __restrict__ bias, const float* __restrict__ g,
                 const float* __restrict__ b, const float* __restrict__ lw,
                 const float* __restrict__ lb, void* __restrict__ out_,
                 const float* __restrict__ x, const int* __restrict__ ends,
                 float* __restrict__ out0, int m_off) {
    __shared__ union SM {
        struct { unsigned char A[34 * 512]; uint4 B[2][4][256]; } st;  // 50176 B
        float Y[32][260];
        int es[L_];
    } sm;

    const int tid = threadIdx.x;
    const int lane = tid & 63, wv = tid >> 6;

    if (blockIdx.x >= 256) {
        // ------------------------------ gather role ------------------------
        const int gb = blockIdx.x - 256;        // 0..383
        const int n = gb / 24;
        const int m0 = m_off + (gb % 24) * 75;
        const int mend = (m0 + 75 < m_off + 1792) ? (m0 + 75) : (m_off + 1792);
        sm.es[tid] = ends[n * L_ + tid];
        __syncthreads();
        const int total = sm.es[L_ - 1];
#pragma unroll 2
        for (int i = 0; i < 10; ++i) {
            int m = m0 + i * 8 + wv;
            if (m < mend) {
                float4 o = {0.f, 0.f, 0.f, 0.f};
                if (m < total) {
                    int lo = -1, hi = L_ - 1;   // first hi with es[hi] > m
                    while (hi - lo > 1) {
                        int mid = (lo + hi) >> 1;
                        if (sm.es[mid] > m) hi = mid; else lo = mid;
                    }
                    o = *(const float4*)&x[((size_t)n * L_ + hi) * D_ + lane * 4];
                }
                *(float4*)&out0[((size_t)n * M_ + m) * D_ + lane * 4] = o;
            }
        }
        return;
    }

    // ---------------------------------- conv role --------------------------
    const int row0 = blockIdx.x * 32;
    const int n = row0 >> 9, l0 = row0 & 511;
    const int wr = (wv >> 2) * 16, wc = (wv & 3) * 64;
    const int fr = lane & 15, fg = lane >> 4;

    f32x4 acc[4];
#pragma unroll
    for (int j = 0; j < 4; ++j) acc[j] = (f32x4){0.f, 0.f, 0.f, 0.f};

    // ---- stage A once: rows r=0..33 <-> l = l0-1+r, bf16, XOR-swizzled ----
    if (BF_IN) {
        for (int idx = tid; idx < 34 * 32; idx += 512) {      // 16B chunks
            int r = idx >> 5, q = idx & 31;
            int l = l0 - 1 + r;
            uint4 v = {0u, 0u, 0u, 0u};
            if (l >= 0 && l < L_)
                v = ((const uint4*)((const unsigned short*)in_ +
                      ((size_t)(n * L_ + l)) * D_))[q];
            int colb = q * 16;
            *(uint4*)(sm.st.A + r * 512 + (colb ^ ((r & 7) << 4))) = v;
        }
    } else {
        for (int idx = tid; idx < 34 * 64; idx += 512) {      // float4 chunks
            int r = idx >> 6, c4 = idx & 63;
            int l = l0 - 1 + r;
            float4 v = {0.f, 0.f, 0.f, 0.f};
            if (l >= 0 && l < L_)
                v = ((const float4*)((const float*)in_ +
                      ((size_t)(n * L_ + l)) * D_))[c4];
            uint2 p;
            p.x = pack2bf(v.x, v.y);
            p.y = pack2bf(v.z, v.w);
            int colb = c4 * 8;
            *(uint2*)(sm.st.A + r * 512 +
                      (((colb & 0x1F0) ^ ((r & 7) << 4)) | (colb & 0xF))) = p;
        }
    }

    // ---- B staging: step ks chunk = Wst + ks*8192 (16KB, contiguous) ----
    const int bco = tid >> 1;
    const int bq0 = (tid & 1) * 2;
    const unsigned short* wbase = Wst + (size_t)bco * 32 + (tid & 1) * 16;

    uint4 c0, c1, n0, n1;
    c0 = *(const uint4*)(wbase);
    c1 = *(const uint4*)(wbase + 8);
    sm.st.B[0][bq0][bco] = c0;
    sm.st.B[0][bq0 + 1][bco] = c1;
    c0 = *(const uint4*)(wbase + 8192);       // ks=1 held in regs
    c1 = *(const uint4*)(wbase + 8192 + 8);
    barrier_lgkm();                            // publishes A + B[0]

    for (int ks = 0; ks < 24; ++ks) {
        if (ks < 22) {                         // issue loads for ks+2
            const unsigned short* wp = wbase + (size_t)(ks + 2) * 8192;
            n0 = *(const uint4*)(wp);
            n1 = *(const uint4*)(wp + 8);
        }
        const int koff = ks >> 3;
        const int ci0b = (ks & 7) * 64;
        const int ar = wr + fr + koff;
        const int acol = (ci0b + fg * 16) ^ ((ar & 7) << 4);
        bf16x8 av = *(const bf16x8*)(sm.st.A + ar * 512 + acol);
        const int rb = ks & 1;
        bf16x8 bv0 = *(const bf16x8*)&sm.st.B[rb][fg][wc + 0 * 16 + fr];
        bf16x8 bv1 = *(const bf16x8*)&sm.st.B[rb][fg][wc + 1 * 16 + fr];
        bf16x8 bv2 = *(const bf16x8*)&sm.st.B[rb][fg][wc + 2 * 16 + fr];
        bf16x8 bv3 = *(const bf16x8*)&sm.st.B[rb][fg][wc + 3 * 16 + fr];
        acc[0] = __builtin_amdgcn_mfma_f32_16x16x32_bf16(av, bv0, acc[0], 0, 0, 0);
        acc[1] = __builtin_amdgcn_mfma_f32_16x16x32_bf16(av, bv1, acc[1], 0, 0, 0);
        acc[2] = __builtin_amdgcn_mfma_f32_16x16x32_bf16(av, bv2, acc[2], 0, 0, 0);
        acc[3] = __builtin_amdgcn_mfma_f32_16x16x32_bf16(av, bv3, acc[3], 0, 0, 0);
        if (ks < 23) {                         // write ks+1's data (in regs)
            sm.st.B[rb ^ 1][bq0][bco] = c0;    // that buf was last read ks-1
            sm.st.B[rb ^ 1][bq0 + 1][bco] = c1;
        }
        c0 = n0; c1 = n1;
        barrier_lgkm();
    }

    // ---- epilogue: relu(acc+bias) into Y (staging dead; published below) ----
#pragma unroll
    for (int j = 0; j < 4; ++j) {
        const int co = wc + j * 16 + fr;
        const float bs = bias[co];
#pragma unroll
        for (int q = 0; q < 4; ++q)
            sm.Y[wr + fg * 4 + q][co] = fmaxf(acc[j][q] + bs, 0.f);
    }
    __syncthreads();

    // ---- per-row LayerNorm; wave wv handles rows wv*4..wv*4+3 ----
    const float4 gv = *(const float4*)&g[lane * 4];
    const float4 bvv = *(const float4*)&b[lane * 4];
    float4 lwv = {0.f, 0.f, 0.f, 0.f};
    if (FINAL) lwv = *(const float4*)&lw[lane * 4];
#pragma unroll
    for (int rr = 0; rr < 4; ++rr) {
        const int r = wv * 4 + rr;
        float4 v = *(const float4*)&sm.Y[r][lane * 4];
        float s = v.x + v.y + v.z + v.w;
        float ss = v.x * v.x + v.y * v.y + v.z * v.z + v.w * v.w;
#pragma unroll
        for (int off = 32; off; off >>= 1) {
            s += __shfl_xor(s, off);
            ss += __shfl_xor(ss, off);
        }
        const float mu = s * (1.f / D_);
        const float var = ss * (1.f / D_) - mu * mu;
        const float rs = rsqrtf(var + LN_EPS);
        const float o0 = (v.x - mu) * rs * gv.x + bvv.x;
        const float o1 = (v.y - mu) * rs * gv.y + bvv.y;
        const float o2 = (v.z - mu) * rs * gv.z + bvv.z;
        const float o3 = (v.w - mu) * rs * gv.w + bvv.w;
        if (!FINAL) {
            ushort4 o;
            o.x = (unsigned short)f2bf_raw(o0);
            o.y = (unsigned short)f2bf_raw(o1);
            o.z = (unsigned short)f2bf_raw(o2);
            o.w = (unsigned short)f2bf_raw(o3);
            *(ushort4*)((unsigned short*)out_ + (size_t)(row0 + r) * D_ + lane * 4) = o;
        } else {
            float dot = o0 * lwv.x + o1 * lwv.y + o2 * lwv.z + o3 * lwv.w;
#pragma unroll
            for (int off = 32; off; off >>= 1) dot += __shfl_xor(dot, off);
            if (lane == 0) ((float*)out_)[row0 + r] = dot + lb[0];
        }
    }
}

// ---------------------------------------------------------------- launch ----
extern "C" void kernel_launch(void* const* d_in, const int* in_sizes, int n_in,
                              void* d_out, int out_size, void* d_ws, size_t ws_size,
                              hipStream_t stream) {
    const float* x   = (const float*)d_in[0];
    const float* w1  = (const float*)d_in[1];
    const float* b1  = (const float*)d_in[2];
    const float* g1  = (const float*)d_in[3];
    const float* be1 = (const float*)d_in[4];
    const float* w2  = (const float*)d_in[5];
    const float* b2  = (const float*)d_in[6];
    const float* g2  = (const float*)d_in[7];
    const float* be2 = (const float*)d_in[8];
    const float* lw  = (const float*)d_in[9];
    const float* lb  = (const float*)d_in[10];
    const int* target = (const int*)d_in[11];

    float* out0 = (float*)d_out;                        // [16, 3584, 256]
    float* log_dur = out0 + (size_t)N_ * M_ * D_;       // [16, 512]

    const size_t E = (size_t)N_ * L_ * D_;
    unsigned short* h1b = (unsigned short*)d_ws;        // [E] bf16
    unsigned short* w1t = h1b + E;                      // [24*8192] bf16
    unsigned short* w2t = w1t + 24 * 8192;              // [24*8192] bf16
    int* ends = (int*)(w2t + 24 * 8192);                // [16*512]

    prep_kernel<<<208, 512, 0, stream>>>(w1, w1t, w2, w2t, target, ends);
    conv_gather<false, false><<<640, 512, 0, stream>>>(
        x, w1t, b1, g1, be1, nullptr, nullptr, h1b, x, ends, out0, 0);
    conv_gather<true, true><<<640, 512, 0, stream>>>(
        h1b, w2t, b2, g2, be2, lw, lb, log_dur, x, ends, out0, M_ / 2);
}

// Round 9
// 37.586 us; speedup vs baseline: 1.3819x; 1.1226x over previous
//
#include <hip/hip_runtime.h>
#include <cstddef>

#define N_ 16
#define L_ 512
#define D_ 256
#define M_ 3584
#define LN_EPS 1e-5f

typedef __attribute__((ext_vector_type(8))) short bf16x8;
typedef __attribute__((ext_vector_type(4))) float f32x4;

__device__ inline unsigned int f2bf_raw(float f) {
    union { float f; unsigned int u; } v; v.f = f;
    return (v.u + 0x7FFFu + ((v.u >> 16) & 1u)) >> 16;   // RNE
}
__device__ inline unsigned int pack2bf(float lo, float hi) {
    return f2bf_raw(lo) | (f2bf_raw(hi) << 16);
}
__device__ inline float bf2f(unsigned int hw) {
    union { unsigned int u; float f; } v; v.u = hw << 16; return v.f;
}
// XOR-swizzled byte offset in the A region (row stride 512 B)
__device__ inline int aswz(int row, int colb) {
    return row * 512 + (((colb & 0x1F0) ^ ((row & 7) << 4)) | (colb & 0xF));
}

// ------------------------------------------------------------------ prep ----
// blocks 0..191: weight fp32 [768 k][256 co] -> fragment-major bf16
//   Wfrag[ks][j][lane][8]: value(lane,e) = W[ks*32 + (lane>>4)*8 + e][j*16 + (lane&15)]
//   (one wave B-fragment load = contiguous 1KB). blocks 192..207: cumsum.
__global__ __launch_bounds__(512)
void prep_kernel(const float* __restrict__ W1, unsigned short* __restrict__ Wt1,
                 const float* __restrict__ W2, unsigned short* __restrict__ Wt2,
                 const int* __restrict__ target, int* __restrict__ ends) {
    __shared__ union { float t[2][32][33]; int s[L_]; } sm;
    const int bid = blockIdx.x;
    if (bid < 192) {
        const int half = threadIdx.x >> 8, st = threadIdx.x & 255;
        const int tile = bid * 2 + half;              // 0..383
        const int kb = (tile % 24) * 32;
        const int cb = ((tile / 24) % 8) * 32;
        const float* W = (tile >= 192) ? W2 : W1;
        unsigned short* Wt = (tile >= 192) ? Wt2 : Wt1;
        const int tx = st & 31, ty = st >> 5;
#pragma unroll
        for (int r = 0; r < 32; r += 8)
            sm.t[half][ty + r][tx] = W[(size_t)(kb + ty + r) * 256 + cb + tx];
        __syncthreads();
        const int jl = st >> 7, l = (st >> 1) & 63, e0 = (st & 1) * 4;
        ushort4 o;
        o.x = (unsigned short)f2bf_raw(sm.t[half][(l >> 4) * 8 + e0 + 0][jl * 16 + (l & 15)]);
        o.y = (unsigned short)f2bf_raw(sm.t[half][(l >> 4) * 8 + e0 + 1][jl * 16 + (l & 15)]);
        o.z = (unsigned short)f2bf_raw(sm.t[half][(l >> 4) * 8 + e0 + 2][jl * 16 + (l & 15)]);
        o.w = (unsigned short)f2bf_raw(sm.t[half][(l >> 4) * 8 + e0 + 3][jl * 16 + (l & 15)]);
        *(ushort4*)(Wt + ((((size_t)(kb >> 5) * 16) + (cb >> 4) + jl) * 64 + l) * 8 + e0) = o;
    } else {
        const int n = bid - 192, t = threadIdx.x;
        sm.s[t] = target[n * L_ + t];
        __syncthreads();
        for (int off = 1; off < L_; off <<= 1) {
            int v = (t >= off) ? sm.s[t - off] : 0;
            __syncthreads();
            sm.s[t] += v;
            __syncthreads();
        }
        ends[n * L_ + t] = sm.s[t];
    }
}

// ------------------------------------------------------ conv K-loop phase ---
// Swapped-operand MFMA: acc[r][j] = mfma(Bfrag_j, Afrag_r, acc) -> lane holds
// D[co = wv*32 + j*16 + fg*4 + q][row = r*16 + fr]. B straight from L2 via
// fragment-major Wfrag (contiguous 1KB/wave), 1-step reg prefetch, NO barriers.
template <int NR, int MAXS>
__device__ __forceinline__ void conv_phase(const unsigned char* Ab,
        const unsigned short* __restrict__ Wf,
        int wv, int lane, int fr, int fg, f32x4 (&acc)[NR][2]) {
    const unsigned short* wb = Wf + ((size_t)(2 * wv) * 64 + lane) * 8;
    uint4 c0 = *(const uint4*)(wb);
    uint4 c1 = *(const uint4*)(wb + 512);
    for (int ks = 0; ks < 24; ++ks) {
        uint4 n0, n1;
        if (ks < 23) {
            const unsigned short* wp = wb + (size_t)(ks + 1) * 8192;
            n0 = *(const uint4*)(wp);
            n1 = *(const uint4*)(wp + 512);
        }
        const int cib = (ks & 7) * 64 + fg * 16;    // byte col base in A row
        const int koff = ks >> 3;                   // conv tap
        bf16x8 av[NR];
#pragma unroll
        for (int r = 0; r < NR; ++r) {
            int ar = r * 16 + fr + koff;
            if (ar > MAXS) ar = MAXS;               // clamp (discarded rows)
            av[r] = *(const bf16x8*)(Ab + ar * 512 + (cib ^ ((ar & 7) << 4)));
        }
        bf16x8 bb0 = *(bf16x8*)&c0, bb1 = *(bf16x8*)&c1;
#pragma unroll
        for (int r = 0; r < NR; ++r) {
            acc[r][0] = __builtin_amdgcn_mfma_f32_16x16x32_bf16(bb0, av[r], acc[r][0], 0, 0, 0);
            acc[r][1] = __builtin_amdgcn_mfma_f32_16x16x32_bf16(bb1, av[r], acc[r][1], 0, 0, 0);
        }
        c0 = n0; c1 = n1;
    }
}

// relu(acc+bias) -> bf16 h rows into A region (8B writes, lane = 4 consec co)
template <int NR, int NROWS>
__device__ __forceinline__ void store_h(unsigned char* Ab, f32x4 (&acc)[NR][2],
        const float* __restrict__ bias, int wv, int fr, int fg) {
#pragma unroll
    for (int r = 0; r < NR; ++r) {
        const int slot = r * 16 + fr;
        if (slot < NROWS) {
#pragma unroll
            for (int j = 0; j < 2; ++j) {
                const int co = wv * 32 + j * 16 + fg * 4;
                const float4 bb = *(const float4*)&bias[co];
                uint2 o;
                o.x = pack2bf(fmaxf(acc[r][j][0] + bb.x, 0.f),
                              fmaxf(acc[r][j][1] + bb.y, 0.f));
                o.y = pack2bf(fmaxf(acc[r][j][2] + bb.z, 0.f),
                              fmaxf(acc[r][j][3] + bb.w, 0.f));
                *(uint2*)(Ab + aswz(slot, 2 * co)) = o;
            }
        }
    }
}

// ------------------------------------------------------------------ mega ----
// blocks [0,256): fused conv1+LN1+conv2+LN2+linear on a 32-row tile
//   (conv1 computes the 34-row halo in-block; h1/h2 never leave LDS).
// blocks [256,768): gather of 112 mel rows each.
__global__ __launch_bounds__(512, 6)
void mega_kernel(const float* __restrict__ x,
                 const unsigned short* __restrict__ Wf1,
                 const unsigned short* __restrict__ Wf2,
                 const float* __restrict__ b1, const float* __restrict__ g1,
                 const float* __restrict__ be1,
                 const float* __restrict__ b2, const float* __restrict__ g2,
                 const float* __restrict__ be2,
                 const float* __restrict__ lw, const float* __restrict__ lb,
                 const int* __restrict__ ends,
                 float* __restrict__ out0, float* __restrict__ log_dur) {
    __shared__ union { unsigned char A[36 * 512]; int es[L_]; } sm;
    const int tid = threadIdx.x, lane = tid & 63, wv = tid >> 6;

    if (blockIdx.x >= 256) {
        // ------------------------------ gather role ------------------------
        const int gb = blockIdx.x - 256;         // 0..511
        const int n = gb >> 5;
        const int m0 = (gb & 31) * 112;
        sm.es[tid] = ends[n * L_ + tid];
        __syncthreads();
        const int total = sm.es[L_ - 1];
#pragma unroll 2
        for (int i = 0; i < 14; ++i) {
            int m = m0 + i * 8 + wv;
            float4 o = {0.f, 0.f, 0.f, 0.f};
            if (m < total) {
                int lo = -1, hi = L_ - 1;        // first hi with es[hi] > m
                while (hi - lo > 1) {
                    int mid = (lo + hi) >> 1;
                    if (sm.es[mid] > m) hi = mid; else lo = mid;
                }
                o = *(const float4*)&x[((size_t)n * L_ + hi) * D_ + lane * 4];
            }
            *(float4*)&out0[((size_t)n * M_ + m) * D_ + lane * 4] = o;
        }
        return;
    }

    // ---------------------------------- conv role --------------------------
    const int row0 = blockIdx.x * 32;
    const int n = row0 >> 9, l0 = row0 & 511;
    const int fr = lane & 15, fg = lane >> 4;

    // ---- stage x once: slots 0..35 <-> l = l0-2+r, bf16, swizzled ----
    for (int idx = tid; idx < 36 * 64; idx += 512) {
        int r = idx >> 6, c4 = idx & 63;
        int l = l0 - 2 + r;
        float4 v = {0.f, 0.f, 0.f, 0.f};
        if (l >= 0 && l < L_)
            v = ((const float4*)(x + ((size_t)(n * L_ + l)) * D_))[c4];
        uint2 p;
        p.x = pack2bf(v.x, v.y);
        p.y = pack2bf(v.z, v.w);
        *(uint2*)(sm.A + aswz(r, c4 * 8)) = p;
    }
    __syncthreads();

    // ---- conv1: h1 slots 0..33 (rows l0-1..l0+32), barrier-free K-loop ----
    f32x4 a1[3][2];
#pragma unroll
    for (int r = 0; r < 3; ++r) { a1[r][0] = (f32x4){0,0,0,0}; a1[r][1] = (f32x4){0,0,0,0}; }
    conv_phase<3, 35>(sm.A, Wf1, wv, lane, fr, fg, a1);
    __syncthreads();                              // all waves done reading x
    store_h<3, 34>(sm.A, a1, b1, wv, fr, fg);
    __syncthreads();

    // ---- LN1 in place; zero out-of-range rows (exact SAME-pad for conv2) --
    {
        const float4 gv = *(const float4*)&g1[lane * 4];
        const float4 bv = *(const float4*)&be1[lane * 4];
        for (int mm = wv; mm < 34; mm += 8) {
            const int addr = aswz(mm, lane * 8);
            const int hrow = l0 - 1 + mm;
            if (hrow < 0 || hrow >= L_) {
                *(uint2*)(sm.A + addr) = (uint2){0u, 0u};
                continue;
            }
            uint2 pv = *(uint2*)(sm.A + addr);
            float v0 = bf2f(pv.x & 0xFFFFu), v1 = bf2f(pv.x >> 16);
            float v2 = bf2f(pv.y & 0xFFFFu), v3 = bf2f(pv.y >> 16);
            float s = v0 + v1 + v2 + v3;
            float ss = v0 * v0 + v1 * v1 + v2 * v2 + v3 * v3;
#pragma unroll
            for (int off = 32; off; off >>= 1) {
                s += __shfl_xor(s, off);
                ss += __shfl_xor(ss, off);
            }
            const float mu = s * (1.f / D_);
            const float var = ss * (1.f / D_) - mu * mu;
            const float rs = rsqrtf(var + LN_EPS);
            uint2 o;
            o.x = pack2bf((v0 - mu) * rs * gv.x + bv.x, (v1 - mu) * rs * gv.y + bv.y);
            o.y = pack2bf((v2 - mu) * rs * gv.z + bv.z, (v3 - mu) * rs * gv.w + bv.w);
            *(uint2*)(sm.A + addr) = o;
        }
    }
    __syncthreads();

    // ---- conv2: output rows l0..l0+31 from h1 slots 0..33 ----
    f32x4 a2[2][2];
#pragma unroll
    for (int r = 0; r < 2; ++r) { a2[r][0] = (f32x4){0,0,0,0}; a2[r][1] = (f32x4){0,0,0,0}; }
    conv_phase<2, 33>(sm.A, Wf2, wv, lane, fr, fg, a2);
    __syncthreads();                              // done reading h1
    store_h<2, 32>(sm.A, a2, b2, wv, fr, fg);
    __syncthreads();

    // ---- LN2 + linear -> log_dur ----
    {
        const float4 gv = *(const float4*)&g2[lane * 4];
        const float4 bv = *(const float4*)&be2[lane * 4];
        const float4 wvv = *(const float4*)&lw[lane * 4];
        for (int mm = wv; mm < 32; mm += 8) {
            uint2 pv = *(uint2*)(sm.A + aswz(mm, lane * 8));
            float v0 = bf2f(pv.x & 0xFFFFu), v1 = bf2f(pv.x >> 16);
            float v2 = bf2f(pv.y & 0xFFFFu), v3 = bf2f(pv.y >> 16);
            float s = v0 + v1 + v2 + v3;
            float ss = v0 * v0 + v1 * v1 + v2 * v2 + v3 * v3;
#pragma unroll
            for (int off = 32; off; off >>= 1) {
                s += __shfl_xor(s, off);
                ss += __shfl_xor(ss, off);
            }
            const float mu = s * (1.f / D_);
            const float var = ss * (1.f / D_) - mu * mu;
            const float rs = rsqrtf(var + LN_EPS);
            float dot = ((v0 - mu) * rs * gv.x + bv.x) * wvv.x
                      + ((v1 - mu) * rs * gv.y + bv.y) * wvv.y
                      + ((v2 - mu) * rs * gv.z + bv.z) * wvv.z
                      + ((v3 - mu) * rs * gv.w + bv.w) * wvv.w;
#pragma unroll
            for (int off = 32; off; off >>= 1) dot += __shfl_xor(dot, off);
            if (lane == 0) log_dur[row0 + mm] = dot + lb[0];
        }
    }
}

// ---------------------------------------------------------------- launch ----
extern "C" void kernel_launch(void* const* d_in, const int* in_sizes, int n_in,
                              void* d_out, int out_size, void* d_ws, size_t ws_size,
                              hipStream_t stream) {
    const float* x   = (const float*)d_in[0];
    const float* w1  = (const float*)d_in[1];
    const float* b1  = (const float*)d_in[2];
    const float* g1  = (const float*)d_in[3];
    const float* be1 = (const float*)d_in[4];
    const float* w2  = (const float*)d_in[5];
    const float* b2  = (const float*)d_in[6];
    const float* g2  = (const float*)d_in[7];
    const float* be2 = (const float*)d_in[8];
    const float* lw  = (const float*)d_in[9];
    const float* lb  = (const float*)d_in[10];
    const int* target = (const int*)d_in[11];

    float* out0 = (float*)d_out;                        // [16, 3584, 256]
    float* log_dur = out0 + (size_t)N_ * M_ * D_;       // [16, 512]

    unsigned short* w1f = (unsigned short*)d_ws;        // [24*16*64*8] bf16
    unsigned short* w2f = w1f + 24 * 8192;              // [24*16*64*8] bf16
    int* ends = (int*)(w2f + 24 * 8192);                // [16*512]

    prep_kernel<<<208, 512, 0, stream>>>(w1, w1f, w2, w2f, target, ends);
    mega_kernel<<<768, 512, 0, stream>>>(x, w1f, w2f, b1, g1, be1,
                                         b2, g2, be2, lw, lb, ends,
                                         out0, log_dur);
}